// Round 6
// baseline (248.869 us; speedup 1.0000x reference)
//
#include <hip/hip_runtime.h>

// RyeElman fused cell, MI355X. B=131072, I=64, H=128, C=16, S=3.
// Wave-independent structure — each WAVE owns a 16-row tile end-to-end;
// A-fragments loaded straight from global (two float4 -> cvt to half8);
// weights in LDS transposed [col][k] (bank-balanced pitches 200/40);
// per-channel norms lane-local; proj via per-s L/R MFMAs, s-sum in-lane.
// Zero barriers in the steady loop. 256 thr/block, grid 512, 79.9KB LDS,
// 4 tiles/wave.
// Launch-bounds law (empirical): arch-VGPR cap = 256/<2nd arg>:
//   (512,4)->64, (512,2)->128, (256,2)->128 (all pinned+spilling),
//   (256,1)->216 used, spill-free (R8: FETCH 63MB, WRITE 90MB = ideal).
// R8 lesson: 216 arch + MFMA accum regs > 256 total -> only 1 wave/SIMD
// resident (Occupancy 10.4%) -> pure latency exposure, dur 112us with all
// pipes <17%.
// R9: register trim to restore 2 waves/SIMD at unchanged traffic:
//   ii-GEMM loop nest swapped to per-t accumulation (acc[8]->one float4v,
//   -28 VGPRs) with proj/tanh/out0 fused into the same t-iteration.
//   Everything else identical to R8.

typedef _Float16 half8  __attribute__((ext_vector_type(8)));
typedef float    float4v __attribute__((ext_vector_type(4)));

#define MFMA16(A, B, C) __builtin_amdgcn_mfma_f32_16x16x32_f16((A), (B), (C), 0, 0, 0)

#define WII_P 200   // k-pitch (halfs) for Wii_t/Wd_t: 400B row -> bank start 4(m+q)%32, 2-way max
#define WLR_P 40    // k-pitch for Wl_t/Wr_t/We_t: 80B row -> bank start 4(5m+q)%32, balanced
#define NTILES 8192
#define NBLOCKS 512
#define NTHR    256
#define NWAVES (NBLOCKS * 4)   // 2048 waves, 4 tiles each

__global__ __launch_bounds__(NTHR, 1) void rye_elman_kernel(
    const float* __restrict__ inv_in,   // [B,64]
    const float* __restrict__ eq_in,    // [B,3]
    const float* __restrict__ inv_hid,  // [B,128]
    const float* __restrict__ eq_hid,   // [B,3,16]
    const float* __restrict__ Wl_g,     // [17,128]
    const float* __restrict__ Wr_g,     // [17,128]
    const float* __restrict__ Wii_g,    // [192,128]
    const float* __restrict__ bii_g,    // [128]
    const float* __restrict__ Wee_g,    // [17,16]
    const float* __restrict__ Wd_g,     // [192,16]
    float* __restrict__ out0,           // [B,128]
    float* __restrict__ out1)           // [B,3,16]
{
    // ---- block-shared transposed f16 weights: Wt[col][k], B-frag = ds_read_b128
    // k-slot mapping for the 17-channel (eq) matrices: slot 0..15 = eq_hid ch 0..15,
    // slot 16 = eq_in channel (row 0 of W), slots 17..31 = zero pad.
    __shared__ __align__(16) _Float16 Wii_t[128 * WII_P];  // 51200 B
    __shared__ __align__(16) _Float16 Wl_t [128 * WLR_P];  // 10240 B
    __shared__ __align__(16) _Float16 Wr_t [128 * WLR_P];  // 10240 B
    __shared__ __align__(16) _Float16 Wd_t [ 16 * WII_P];  //  6400 B
    __shared__ __align__(16) _Float16 We_t [ 16 * WLR_P];  //  1280 B
    __shared__ float bii_s[128];                           //   512 B  => 79872 B total

    const int tid = threadIdx.x;

    // zero the padded eq-weight tiles first (slots >=17 must be 0)
    for (int i = tid; i < 128 * WLR_P; i += NTHR) { Wl_t[i] = (_Float16)0.f; Wr_t[i] = (_Float16)0.f; }
    for (int i = tid; i < 16 * WLR_P; i += NTHR)  We_t[i] = (_Float16)0.f;
    __syncthreads();
    for (int i = tid; i < 192 * 128; i += NTHR) {
        const int k = i >> 7, c = i & 127;
        Wii_t[c * WII_P + k] = (_Float16)Wii_g[i];
    }
    for (int i = tid; i < 17 * 128; i += NTHR) {
        const int r = i >> 7, c = i & 127, sl = (r == 0) ? 16 : r - 1;
        Wl_t[c * WLR_P + sl] = (_Float16)Wl_g[i];
        Wr_t[c * WLR_P + sl] = (_Float16)Wr_g[i];
    }
    for (int i = tid; i < 192 * 16; i += NTHR) {
        const int k = i >> 4, c = i & 15;
        Wd_t[c * WII_P + k] = (_Float16)Wd_g[i];
    }
    for (int i = tid; i < 17 * 16; i += NTHR) {
        const int r = i >> 4, c = i & 15, sl = (r == 0) ? 16 : r - 1;
        We_t[c * WLR_P + sl] = (_Float16)Wee_g[i];
    }
    if (tid < 128) bii_s[tid] = bii_g[tid];
    __syncthreads();
    // ---- no more barriers: every wave is independent from here on

    const int lane = tid & 63;
    const int q    = lane >> 4;   // k-chunk (A) / row group (C)
    const int m    = lane & 15;   // A-row / C-col
    const int wgid = (blockIdx.x << 2) + (tid >> 6);

    for (int tile = wgid; tile < NTILES; tile += NWAVES) {
        const long base = (long)tile << 4;
        const long rowm = base + m;

        // ---- A-side global loads, straight into registers
        float4 av[6][2];                     // inv_comb features 32s+8q .. +7 of row m
        {
            const float4* pi = (const float4*)(inv_in  + rowm * 64);
            const float4* ph = (const float4*)(inv_hid + rowm * 128);
#pragma unroll
            for (int s = 0; s < 2; ++s) { av[s][0] = pi[8 * s + 2 * q]; av[s][1] = pi[8 * s + 2 * q + 1]; }
#pragma unroll
            for (int s = 0; s < 4; ++s) { av[s + 2][0] = ph[8 * s + 2 * q]; av[s + 2][1] = ph[8 * s + 2 * q + 1]; }
        }
        float xq[3][8];                      // eq_comb slots 8q..8q+7, all 3 spatial s
#pragma unroll
        for (int s = 0; s < 3; ++s)
#pragma unroll
            for (int j = 0; j < 8; ++j) xq[s][j] = 0.f;
        if (q < 2) {                         // slots 0..15 = eq_hid channels
            const float4* pe = (const float4*)(eq_hid + rowm * 48);
#pragma unroll
            for (int s = 0; s < 3; ++s) {
                const float4 u0 = pe[4 * s + 2 * q], u1 = pe[4 * s + 2 * q + 1];
                xq[s][0] = u0.x; xq[s][1] = u0.y; xq[s][2] = u0.z; xq[s][3] = u0.w;
                xq[s][4] = u1.x; xq[s][5] = u1.y; xq[s][6] = u1.z; xq[s][7] = u1.w;
            }
        } else if (q == 2) {                 // slot 16 = eq_in channel (j==0 only)
#pragma unroll
            for (int s = 0; s < 3; ++s) xq[s][0] = eq_in[rowm * 3 + s];
        }                                    // q==3: all pad, stays 0

        // ---- convert inv_comb to A-fragments
        half8 aii[6];
#pragma unroll
        for (int s = 0; s < 6; ++s) {
            half8 h;
            h[0] = (_Float16)av[s][0].x; h[1] = (_Float16)av[s][0].y;
            h[2] = (_Float16)av[s][0].z; h[3] = (_Float16)av[s][0].w;
            h[4] = (_Float16)av[s][1].x; h[5] = (_Float16)av[s][1].y;
            h[6] = (_Float16)av[s][1].z; h[7] = (_Float16)av[s][1].w;
            aii[s] = h;
        }
        // ---- lane-local squared-norms (per channel, summed over s) + eq fragments
        float rn[8];
#pragma unroll
        for (int j = 0; j < 8; ++j) {
            const float nn = fmaf(xq[0][j], xq[0][j],
                             fmaf(xq[1][j], xq[1][j],
                             fmaf(xq[2][j], xq[2][j], 1e-6f)));
            rn[j] = __builtin_amdgcn_rcpf(nn);   // pad lanes: rcp(1e-6) * 0 = 0, harmless
        }
        half8 xr[3], xnh[3];
#pragma unroll
        for (int s = 0; s < 3; ++s) {
            half8 hr, hn;
#pragma unroll
            for (int j = 0; j < 8; ++j) {
                hr[j] = (_Float16)xq[s][j];
                hn[j] = (_Float16)(xq[s][j] * rn[j]);
            }
            xr[s] = hr; xnh[s] = hn;
        }

        const float4v z4 = (float4v){0.f, 0.f, 0.f, 0.f};

        // ---- damping gate (192->16): 6 chained MFMAs on aii
        float4v gacc = z4;
#pragma unroll
        for (int s = 0; s < 6; ++s)
            gacc = MFMA16(aii[s], *(const half8*)&Wd_t[m * WII_P + 32 * s + 8 * q], gacc);

        // ---- per-t: ii GEMM column-block (192->16 cols) + proj + tanh + out0.
        // acc lives one t-iteration only (was acc[8] across the tile: -28 VGPR,
        // restores 2 waves/SIMD residency).
#pragma unroll
        for (int t = 0; t < 8; ++t) {
            const int col = 16 * t + m;
            float4v acc = z4;
#pragma unroll
            for (int s = 0; s < 6; ++s)
                acc = MFMA16(aii[s], *(const half8*)&Wii_t[col * WII_P + 32 * s + 8 * q], acc);
            const half8 bl = *(const half8*)&Wl_t[col * WLR_P + 8 * q];
            const half8 br = *(const half8*)&Wr_t[col * WLR_P + 8 * q];
            const float4v L0 = MFMA16(xnh[0], bl, z4);
            const float4v R0 = MFMA16(xnh[0], br, z4);
            const float4v L1 = MFMA16(xnh[1], bl, z4);
            const float4v R1 = MFMA16(xnh[1], br, z4);
            const float4v L2 = MFMA16(xnh[2], bl, z4);
            const float4v R2 = MFMA16(xnh[2], br, z4);
            const float bb = bii_s[col];
#pragma unroll
            for (int r = 0; r < 4; ++r) {
                const float pr = L0[r] * R0[r] + L1[r] * R1[r] + L2[r] * R2[r];
                const float x  = acc[r] + pr + bb;
                const float e  = __expf(2.f * x);              // tanh = 1 - 2/(e^{2x}+1)
                out0[(base + 4 * q + r) * 128 + col] = 1.f - 2.f * __builtin_amdgcn_rcpf(e + 1.f);
            }
        }

        // ---- ee (17->16 per s) + damping epilogue + out1 store (exact f32 eq_hid)
        {
            const half8 be = *(const half8*)&We_t[m * WLR_P + 8 * q];
            const float4v E0 = MFMA16(xr[0], be, z4);
            const float4v E1 = MFMA16(xr[1], be, z4);
            const float4v E2 = MFMA16(xr[2], be, z4);
#pragma unroll
            for (int r = 0; r < 4; ++r) {
                const long  rw = base + 4 * q + r;
                const float g  = gacc[r];
                const float* eh = eq_hid + rw * 48 + m;        // cache-hot: just streamed
                out1[rw * 48 +      m] = E0[r] + eh[0]  * g;
                out1[rw * 48 + 16 + m] = E1[r] + eh[16] * g;
                out1[rw * 48 + 32 + m] = E2[r] + eh[32] * g;
            }
        }
    }
}

extern "C" void kernel_launch(void* const* d_in, const int* in_sizes, int n_in,
                              void* d_out, int out_size, void* d_ws, size_t ws_size,
                              hipStream_t stream) {
    const float* inv_in  = (const float*)d_in[0];
    const float* eq_in   = (const float*)d_in[1];
    const float* inv_hid = (const float*)d_in[2];
    const float* eq_hid  = (const float*)d_in[3];
    const float* Wl      = (const float*)d_in[4];
    const float* Wr      = (const float*)d_in[5];
    const float* Wii     = (const float*)d_in[6];
    const float* bii     = (const float*)d_in[7];
    const float* Wee     = (const float*)d_in[8];
    const float* Wd      = (const float*)d_in[9];
    float* o0 = (float*)d_out;
    float* o1 = o0 + (size_t)131072 * 128;
    hipLaunchKernelGGL(rye_elman_kernel, dim3(NBLOCKS), dim3(NTHR), 0, stream,
                       inv_in, eq_in, inv_hid, eq_hid, Wl, Wr, Wii, bii, Wee, Wd, o0, o1);
}

// Round 7
// 228.240 us; speedup vs baseline: 1.0904x; 1.0904x over previous
//
#include <hip/hip_runtime.h>

// RyeElman fused cell, MI355X. B=131072, I=64, H=128, C=16, S=3.
// Wave-independent structure — each WAVE owns a 16-row tile end-to-end;
// A-fragments loaded straight from global (two float4 -> cvt to half8);
// weights in LDS transposed [col][k] (bank-balanced pitches 200/40);
// per-channel norms lane-local; proj via per-s L/R MFMAs, s-sum in-lane.
// Zero syncthreads in the steady loop. 256 thr/block, grid 512, 79.9KB LDS,
// 4 tiles/wave.
// Empirical laws so far:
//   - launch_bounds 2nd arg w -> arch-VGPR cap 256/w; any cap below the
//     natural live set spills through scratch (R6/R7: +100-500MB HBM).
//   - residency: 128-VGPR waves -> 2 blocks/CU (occ 21%); 216 -> 1 block/CU
//     (occ 10.4%, 1 wave/SIMD). 2-wave/SIMD threshold in (128,216].
//   - R9 lesson: without a cap the scheduler hoists ds_reads across all 8
//     t-iterations and re-inflates to 216 regs regardless of source-level
//     lifetimes. Allocation is schedule-driven, not source-driven.
// R10: keep (256,1) (capless = spill-free) and pin the schedule instead:
//   __builtin_amdgcn_sched_barrier(0) after load/convert phase, gate chain,
//   each t-iteration, and tile end. Per-phase live peak ~100-130 -> natural
//   allocation ~130-160 -> 2 blocks/CU resident; TLP replaces the removed
//   ILP. Also: pr accumulated pairwise (L*R += ) to cut transient pressure.

typedef _Float16 half8  __attribute__((ext_vector_type(8)));
typedef float    float4v __attribute__((ext_vector_type(4)));

#define MFMA16(A, B, C) __builtin_amdgcn_mfma_f32_16x16x32_f16((A), (B), (C), 0, 0, 0)
#define SCHED_FENCE() __builtin_amdgcn_sched_barrier(0)

#define WII_P 200   // k-pitch (halfs) for Wii_t/Wd_t: 400B row -> bank start 4(m+q)%32, 2-way max
#define WLR_P 40    // k-pitch for Wl_t/Wr_t/We_t: 80B row -> bank start 4(5m+q)%32, balanced
#define NTILES 8192
#define NBLOCKS 512
#define NTHR    256
#define NWAVES (NBLOCKS * 4)   // 2048 waves, 4 tiles each

__global__ __launch_bounds__(NTHR, 1) void rye_elman_kernel(
    const float* __restrict__ inv_in,   // [B,64]
    const float* __restrict__ eq_in,    // [B,3]
    const float* __restrict__ inv_hid,  // [B,128]
    const float* __restrict__ eq_hid,   // [B,3,16]
    const float* __restrict__ Wl_g,     // [17,128]
    const float* __restrict__ Wr_g,     // [17,128]
    const float* __restrict__ Wii_g,    // [192,128]
    const float* __restrict__ bii_g,    // [128]
    const float* __restrict__ Wee_g,    // [17,16]
    const float* __restrict__ Wd_g,     // [192,16]
    float* __restrict__ out0,           // [B,128]
    float* __restrict__ out1)           // [B,3,16]
{
    // ---- block-shared transposed f16 weights: Wt[col][k], B-frag = ds_read_b128
    // k-slot mapping for the 17-channel (eq) matrices: slot 0..15 = eq_hid ch 0..15,
    // slot 16 = eq_in channel (row 0 of W), slots 17..31 = zero pad.
    __shared__ __align__(16) _Float16 Wii_t[128 * WII_P];  // 51200 B
    __shared__ __align__(16) _Float16 Wl_t [128 * WLR_P];  // 10240 B
    __shared__ __align__(16) _Float16 Wr_t [128 * WLR_P];  // 10240 B
    __shared__ __align__(16) _Float16 Wd_t [ 16 * WII_P];  //  6400 B
    __shared__ __align__(16) _Float16 We_t [ 16 * WLR_P];  //  1280 B
    __shared__ float bii_s[128];                           //   512 B  => 79872 B total

    const int tid = threadIdx.x;

    // zero the padded eq-weight tiles first (slots >=17 must be 0)
    for (int i = tid; i < 128 * WLR_P; i += NTHR) { Wl_t[i] = (_Float16)0.f; Wr_t[i] = (_Float16)0.f; }
    for (int i = tid; i < 16 * WLR_P; i += NTHR)  We_t[i] = (_Float16)0.f;
    __syncthreads();
    for (int i = tid; i < 192 * 128; i += NTHR) {
        const int k = i >> 7, c = i & 127;
        Wii_t[c * WII_P + k] = (_Float16)Wii_g[i];
    }
    for (int i = tid; i < 17 * 128; i += NTHR) {
        const int r = i >> 7, c = i & 127, sl = (r == 0) ? 16 : r - 1;
        Wl_t[c * WLR_P + sl] = (_Float16)Wl_g[i];
        Wr_t[c * WLR_P + sl] = (_Float16)Wr_g[i];
    }
    for (int i = tid; i < 192 * 16; i += NTHR) {
        const int k = i >> 4, c = i & 15;
        Wd_t[c * WII_P + k] = (_Float16)Wd_g[i];
    }
    for (int i = tid; i < 17 * 16; i += NTHR) {
        const int r = i >> 4, c = i & 15, sl = (r == 0) ? 16 : r - 1;
        We_t[c * WLR_P + sl] = (_Float16)Wee_g[i];
    }
    if (tid < 128) bii_s[tid] = bii_g[tid];
    __syncthreads();
    // ---- no more syncthreads: every wave is independent from here on

    const int lane = tid & 63;
    const int q    = lane >> 4;   // k-chunk (A) / row group (C)
    const int m    = lane & 15;   // A-row / C-col
    const int wgid = (blockIdx.x << 2) + (tid >> 6);

    for (int tile = wgid; tile < NTILES; tile += NWAVES) {
        const long base = (long)tile << 4;
        const long rowm = base + m;

        // ---- A-side global loads, straight into registers
        float4 av[6][2];                     // inv_comb features 32s+8q .. +7 of row m
        {
            const float4* pi = (const float4*)(inv_in  + rowm * 64);
            const float4* ph = (const float4*)(inv_hid + rowm * 128);
#pragma unroll
            for (int s = 0; s < 2; ++s) { av[s][0] = pi[8 * s + 2 * q]; av[s][1] = pi[8 * s + 2 * q + 1]; }
#pragma unroll
            for (int s = 0; s < 4; ++s) { av[s + 2][0] = ph[8 * s + 2 * q]; av[s + 2][1] = ph[8 * s + 2 * q + 1]; }
        }
        float xq[3][8];                      // eq_comb slots 8q..8q+7, all 3 spatial s
#pragma unroll
        for (int s = 0; s < 3; ++s)
#pragma unroll
            for (int j = 0; j < 8; ++j) xq[s][j] = 0.f;
        if (q < 2) {                         // slots 0..15 = eq_hid channels
            const float4* pe = (const float4*)(eq_hid + rowm * 48);
#pragma unroll
            for (int s = 0; s < 3; ++s) {
                const float4 u0 = pe[4 * s + 2 * q], u1 = pe[4 * s + 2 * q + 1];
                xq[s][0] = u0.x; xq[s][1] = u0.y; xq[s][2] = u0.z; xq[s][3] = u0.w;
                xq[s][4] = u1.x; xq[s][5] = u1.y; xq[s][6] = u1.z; xq[s][7] = u1.w;
            }
        } else if (q == 2) {                 // slot 16 = eq_in channel (j==0 only)
#pragma unroll
            for (int s = 0; s < 3; ++s) xq[s][0] = eq_in[rowm * 3 + s];
        }                                    // q==3: all pad, stays 0

        // ---- convert inv_comb to A-fragments
        half8 aii[6];
#pragma unroll
        for (int s = 0; s < 6; ++s) {
            half8 h;
            h[0] = (_Float16)av[s][0].x; h[1] = (_Float16)av[s][0].y;
            h[2] = (_Float16)av[s][0].z; h[3] = (_Float16)av[s][0].w;
            h[4] = (_Float16)av[s][1].x; h[5] = (_Float16)av[s][1].y;
            h[6] = (_Float16)av[s][1].z; h[7] = (_Float16)av[s][1].w;
            aii[s] = h;
        }
        // ---- lane-local squared-norms (per channel, summed over s) + eq fragments
        float rn[8];
#pragma unroll
        for (int j = 0; j < 8; ++j) {
            const float nn = fmaf(xq[0][j], xq[0][j],
                             fmaf(xq[1][j], xq[1][j],
                             fmaf(xq[2][j], xq[2][j], 1e-6f)));
            rn[j] = __builtin_amdgcn_rcpf(nn);   // pad lanes: rcp(1e-6) * 0 = 0, harmless
        }
        half8 xr[3], xnh[3];
#pragma unroll
        for (int s = 0; s < 3; ++s) {
            half8 hr, hn;
#pragma unroll
            for (int j = 0; j < 8; ++j) {
                hr[j] = (_Float16)xq[s][j];
                hn[j] = (_Float16)(xq[s][j] * rn[j]);
            }
            xr[s] = hr; xnh[s] = hn;
        }
        SCHED_FENCE();   // end of load/convert phase: av/xq die here

        const float4v z4 = (float4v){0.f, 0.f, 0.f, 0.f};

        // ---- damping gate (192->16): 6 chained MFMAs on aii
        float4v gacc = z4;
#pragma unroll
        for (int s = 0; s < 6; ++s)
            gacc = MFMA16(aii[s], *(const half8*)&Wd_t[m * WII_P + 32 * s + 8 * q], gacc);
        SCHED_FENCE();   // gate chain done

        // ---- per-t: ii GEMM column-block + proj + tanh + out0, fenced per
        // iteration so ds_reads of later t's can't be hoisted (keeps the
        // per-phase live peak ~120 regs -> 2 waves/SIMD residency).
#pragma unroll
        for (int t = 0; t < 8; ++t) {
            const int col = 16 * t + m;
            float4v acc = z4;
#pragma unroll
            for (int s = 0; s < 6; ++s)
                acc = MFMA16(aii[s], *(const half8*)&Wii_t[col * WII_P + 32 * s + 8 * q], acc);
            const half8 bl = *(const half8*)&Wl_t[col * WLR_P + 8 * q];
            const half8 br = *(const half8*)&Wr_t[col * WLR_P + 8 * q];
            // pr accumulated pairwise: only one L/R pair live at a time
            float4v pr;
            {
                const float4v L0 = MFMA16(xnh[0], bl, z4);
                const float4v R0 = MFMA16(xnh[0], br, z4);
                pr = L0 * R0;
            }
            {
                const float4v L1 = MFMA16(xnh[1], bl, z4);
                const float4v R1 = MFMA16(xnh[1], br, z4);
                pr += L1 * R1;
            }
            {
                const float4v L2 = MFMA16(xnh[2], bl, z4);
                const float4v R2 = MFMA16(xnh[2], br, z4);
                pr += L2 * R2;
            }
            const float bb = bii_s[col];
#pragma unroll
            for (int r = 0; r < 4; ++r) {
                const float x = acc[r] + pr[r] + bb;
                const float e = __expf(2.f * x);               // tanh = 1 - 2/(e^{2x}+1)
                out0[(base + 4 * q + r) * 128 + col] = 1.f - 2.f * __builtin_amdgcn_rcpf(e + 1.f);
            }
            SCHED_FENCE();
        }

        // ---- ee (17->16 per s) + damping epilogue + out1 store (exact f32 eq_hid)
        {
            const half8 be = *(const half8*)&We_t[m * WLR_P + 8 * q];
            const float4v E0 = MFMA16(xr[0], be, z4);
            const float4v E1 = MFMA16(xr[1], be, z4);
            const float4v E2 = MFMA16(xr[2], be, z4);
#pragma unroll
            for (int r = 0; r < 4; ++r) {
                const long  rw = base + 4 * q + r;
                const float g  = gacc[r];
                const float* eh = eq_hid + rw * 48 + m;        // cache-hot: just streamed
                out1[rw * 48 +      m] = E0[r] + eh[0]  * g;
                out1[rw * 48 + 16 + m] = E1[r] + eh[16] * g;
                out1[rw * 48 + 32 + m] = E2[r] + eh[32] * g;
            }
        }
        SCHED_FENCE();   // tile end: no cross-tile hoisting
    }
}

extern "C" void kernel_launch(void* const* d_in, const int* in_sizes, int n_in,
                              void* d_out, int out_size, void* d_ws, size_t ws_size,
                              hipStream_t stream) {
    const float* inv_in  = (const float*)d_in[0];
    const float* eq_in   = (const float*)d_in[1];
    const float* inv_hid = (const float*)d_in[2];
    const float* eq_hid  = (const float*)d_in[3];
    const float* Wl      = (const float*)d_in[4];
    const float* Wr      = (const float*)d_in[5];
    const float* Wii     = (const float*)d_in[6];
    const float* bii     = (const float*)d_in[7];
    const float* Wee     = (const float*)d_in[8];
    const float* Wd      = (const float*)d_in[9];
    float* o0 = (float*)d_out;
    float* o1 = o0 + (size_t)131072 * 128;
    hipLaunchKernelGGL(rye_elman_kernel, dim3(NBLOCKS), dim3(NTHR), 0, stream,
                       inv_in, eq_in, inv_hid, eq_hid, Wl, Wr, Wii, bii, Wee, Wd, o0, o1);
}